// Round 13
// baseline (496.643 us; speedup 1.0000x reference)
//
#include <hip/hip_runtime.h>
#include <hip/hip_bf16.h>
#include <cstdint>
#include <cstddef>

#define N_NODES 50000
#define N_EDGES 800000
#define D_IN 128
#define D_H 512
#define D_OUT 256
#define N_GRAPHS 512

#define BM 128
#define BN 128
#define BK 32
#define NBLK ((N_NODES + 255) / 256)   // 196
#define CT_SW 132                      // C-tile LDS stride in ushorts (264 B)
#define N_MT 391                       // m-tiles for M=50000
#define MT_PER_XCD 49                  // ceil(391/8)

// fixed-point scales: x quantized to int16 (scale 2^12, |x|<8 guaranteed by
// clamp), accumulated in int32 -> bitwise-deterministic aggregation.
#define XQ_SCALE 4096.0f
#define XQ_INV (1.0f / 4096.0f)

typedef __bf16 v8bf __attribute__((ext_vector_type(8)));
typedef float v4f __attribute__((ext_vector_type(4)));
typedef int v4i __attribute__((ext_vector_type(4)));

__device__ __forceinline__ float bf2f(unsigned short b) {
  return __uint_as_float(((unsigned int)b) << 16);
}
__device__ __forceinline__ unsigned short f2bf(float f) {
  unsigned int u = __float_as_uint(f);
  u += 0x7FFFu + ((u >> 16) & 1u);   // RNE
  return (unsigned short)(u >> 16);
}

__device__ __forceinline__ void gload_lds16(const void* g, void* l) {
  __builtin_amdgcn_global_load_lds(
      (const __attribute__((address_space(1))) void*)g,
      (__attribute__((address_space(3))) void*)l, 16, 0, 0);
}

// ---------------- prep: zero deg + dtype detect (block 0) -------------------
__global__ __launch_bounds__(256) void k_prep(const void* __restrict__ x,
                                              const void* __restrict__ ei,
                                              const void* __restrict__ batch,
                                              int* __restrict__ deg,
                                              int* __restrict__ flags) {
  int i = blockIdx.x * 256 + threadIdx.x;
  if (i < N_NODES) deg[i] = 0;
  if (blockIdx.x != 0) return;
  __shared__ int cnt[3];
  int t = threadIdx.x;
  if (t < 3) cnt[t] = 0;
  __syncthreads();
  const unsigned short* xs = (const unsigned short*)x;
  int c0 = 0;
  for (int k = t; k < 4096; k += 256) {
    unsigned int e = (xs[k] >> 7) & 0xFFu;
    if (e >= 0x90u) c0++;   // |v|>=2^17 as bf16: impossible for N(0,1)
  }
  atomicAdd(&cnt[0], c0);
  const int* e32 = (const int*)ei;
  int c1 = 0;
  for (int k = t; k < 512; k += 256)
    if (e32[2 * k + 1] != 0) c1++;   // int64 -> high words all zero
  atomicAdd(&cnt[1], c1);
  const int* b32 = (const int*)batch;
  int c2 = 0;
  {
    int w = (N_NODES - 512) + 2 * t + 1;   // odd word near tail, < N_NODES
    if (b32[w] != 0) c2++;
  }
  atomicAdd(&cnt[2], c2);
  __syncthreads();
  if (t == 0) {
    flags[0] = (cnt[0] > 16) ? 1 : 0;
    flags[1] = (cnt[1] == 0) ? 1 : 0;
    flags[2] = (cnt[2] == 0) ? 1 : 0;
  }
}

// ---------------- fused weight transposes (B^T layout) ----------------------
__global__ void k_transpose_all(const void* W1, const void* W2, const void* W3,
                                const void* W4, const void* Wl,
                                unsigned short* W1T, unsigned short* W2T,
                                unsigned short* W3T, unsigned short* W4T,
                                unsigned short* WlT,
                                const int* __restrict__ flags) {
  int i = blockIdx.x * 256 + threadIdx.x;
  const void* src;
  unsigned short* dst;
  int R, C, j;
  if (i < 65536)            { src = W1; dst = W1T; R = 128; C = 512; j = i; }
  else if (i < 327680)      { src = W2; dst = W2T; R = 512; C = 512; j = i - 65536; }
  else if (i < 589824)      { src = W3; dst = W3T; R = 512; C = 512; j = i - 327680; }
  else if (i < 851968)      { src = W4; dst = W4T; R = 512; C = 512; j = i - 589824; }
  else if (i < 983040)      { src = Wl; dst = WlT; R = 512; C = 256; j = i - 851968; }
  else return;
  int r = j / C, c = j - r * C;
  unsigned short v = flags[0] ? f2bf(((const float*)src)[j])
                              : ((const unsigned short*)src)[j];
  dst[c * R + r] = v;
}

// ---------------- x -> packed int16 fixed-point (scale 2^12) ----------------
// Cuts gather VALU: per-edge work becomes load + 2 sext + 2 int adds.
__global__ __launch_bounds__(256) void k_cvtx(const void* __restrict__ x,
                                              const int* __restrict__ flags,
                                              unsigned int* __restrict__ xi) {
  int i = blockIdx.x * 256 + threadIdx.x;   // dword index (2 values)
  if (i >= N_NODES * D_IN / 2) return;
  float v0, v1;
  if (flags[0]) {
    const float* xf = (const float*)x + (size_t)i * 2;
    v0 = xf[0];
    v1 = xf[1];
  } else {
    unsigned int p = ((const unsigned int*)x)[i];
    v0 = __uint_as_float((p & 0xFFFFu) << 16);
    v1 = __uint_as_float(p & 0xFFFF0000u);
  }
  int q0 = __float2int_rn(fminf(fmaxf(v0, -7.99f), 7.99f) * XQ_SCALE);
  int q1 = __float2int_rn(fminf(fmaxf(v1, -7.99f), 7.99f) * XQ_SCALE);
  xi[i] = ((unsigned int)q0 & 0xFFFFu) | ((unsigned int)q1 << 16);
}

// ---------------- CSR build -------------------------------------------------
__global__ void k_count(const int* __restrict__ ei, int* __restrict__ deg,
                        const int* __restrict__ flags, int ne) {
  int e = blockIdx.x * 256 + threadIdx.x;
  if (e >= ne) return;
  int d = flags[1] ? ei[2 * ((size_t)ne + e)] : ei[(size_t)ne + e];
  atomicAdd(&deg[d], 1);
}

__global__ __launch_bounds__(256) void k_scanA(const int* __restrict__ deg,
                                               int* __restrict__ rowptr,
                                               int* __restrict__ part) {
  __shared__ int sh[256];
  int t = threadIdx.x;
  int i = blockIdx.x * 256 + t;
  int v = (i < N_NODES) ? deg[i] : 0;
  sh[t] = v;
  __syncthreads();
  for (int o = 1; o < 256; o <<= 1) {
    int a = sh[t];
    int b = (t >= o) ? sh[t - o] : 0;
    __syncthreads();
    sh[t] = a + b;
    __syncthreads();
  }
  if (i < N_NODES) rowptr[i] = sh[t] - v;   // local exclusive
  if (t == 255) part[blockIdx.x] = sh[255];
}

__global__ __launch_bounds__(256) void k_scanB(int* __restrict__ part,
                                               int* __restrict__ rowptr) {
  __shared__ int sh[256];
  int t = threadIdx.x;
  int v = (t < NBLK) ? part[t] : 0;
  sh[t] = v;
  __syncthreads();
  for (int o = 1; o < 256; o <<= 1) {
    int a = sh[t];
    int b = (t >= o) ? sh[t - o] : 0;
    __syncthreads();
    sh[t] = a + b;
    __syncthreads();
  }
  if (t < NBLK) part[t] = sh[t] - v;   // exclusive base per block
  if (t == 0) rowptr[N_NODES] = sh[255];
}

__global__ __launch_bounds__(256) void k_scanC(int* __restrict__ rowptr,
                                               const int* __restrict__ part,
                                               int* __restrict__ cur) {
  int i = blockIdx.x * 256 + threadIdx.x;
  if (i < N_NODES) {
    int r = rowptr[i] + part[blockIdx.x];
    rowptr[i] = r;
    cur[i] = r;
  }
}

// Full-parallel fill, plain loads+stores (measured best: R7; nt variants and
// XCD-pinning all regressed in R8-R10).
__global__ void k_fill(const int* __restrict__ ei, int* __restrict__ cur,
                       int* __restrict__ elist, const int* __restrict__ flags,
                       int ne) {
  int e = blockIdx.x * 256 + threadIdx.x;
  if (e >= ne) return;
  bool fe64 = flags[1] != 0;
  int s = fe64 ? ei[2 * (size_t)e] : ei[e];
  int d = fe64 ? ei[2 * ((size_t)ne + e)] : ei[(size_t)ne + e];
  int pos = atomicAdd(&cur[d], 1);
  elist[pos] = s;
}

// ---------------- gather aggregation (one wave per node, int16 source) ------
// readlane -> SGPR row base (no ds_bpermute); int16 adds, int32 accumulate.
__global__ __launch_bounds__(256) void k_gather(
    const unsigned int* __restrict__ xi, const int* __restrict__ rowptr,
    const int* __restrict__ elist, unsigned int* __restrict__ h0) {
  int node = blockIdx.x * 4 + (threadIdx.x >> 6);
  if (node >= N_NODES) return;
  int lane = threadIdx.x & 63;
  int s0 = rowptr[node], s1 = rowptr[node + 1];
  unsigned int px = xi[(size_t)node * (D_IN / 2) + lane];
  int a0 = (int)(short)(px & 0xFFFFu);
  int a1 = (int)px >> 16;
  for (int j0 = s0; j0 < s1; j0 += 64) {
    int jj = j0 + lane;
    int ev = (jj < s1) ? elist[jj] : 0;
    int cnt = s1 - j0;
    cnt = cnt < 64 ? cnt : 64;
    for (int j = 0; j < cnt; ++j) {
      int s = __builtin_amdgcn_readlane(ev, j);    // wave-uniform SGPR
      unsigned int p = xi[(size_t)s * (D_IN / 2) + lane];
      a0 += (int)(short)(p & 0xFFFFu);
      a1 += (int)p >> 16;
    }
  }
  unsigned int lo = f2bf((float)a0 * XQ_INV);
  unsigned int hi = f2bf((float)a1 * XQ_INV);
  h0[(size_t)node * (D_IN / 2) + lane] = lo | (hi << 16);
}

// ---------------- MFMA GEMM: C = act(A @ W + bias), BK=32 dbuf -------------
// Swizzle g(r)=(r>>1)&3 (conflict-free, R11). Epilogue sector-complete store
// map (R12: WRITE 97->52 MB). 5 blocks/CU (160 KB LDS): R13 occupancy bump.
// ACT: 0 = LeakyReLU(1.5), 1 = ReLU, 2 = none. OUTF32: write f32 else bf16.
template <int ACT, bool OUTF32, bool SWZ>
__global__ __launch_bounds__(256, 5) void gemm_bt(
    const unsigned short* __restrict__ A,
    const unsigned short* __restrict__ BT,
    const void* __restrict__ bias, const int* __restrict__ flags,
    void* __restrict__ Cout, int M, int K, int Nc) {
  __shared__ __align__(16) unsigned short smem[2][BM * BK + BN * BK];  // 32 KB

  const int tid  = threadIdx.x;
  const int wave = tid >> 6;
  const int lane = tid & 63;
  const int quad = lane >> 4;
  const int l15  = lane & 15;
  int m0, n0;
  if (SWZ) {
    int xcd = blockIdx.x & 7;
    int l = blockIdx.x >> 3;                 // 0..195
    int mt = xcd * MT_PER_XCD + (l >> 2);    // 49 m-tiles per XCD
    if (mt >= N_MT) return;                  // 8 padded blocks exit
    m0 = mt * BM;
    n0 = (l & 3) * BN;
  } else {
    n0 = blockIdx.x * BN;
    m0 = blockIdx.y * BM;
  }
  const int wm = (wave >> 1) * 64;
  const int wn = (wave & 1) * 64;
  const bool fm = flags[0] != 0;

  v4f acc[4][4];
#pragma unroll
  for (int i = 0; i < 4; ++i)
#pragma unroll
    for (int j = 0; j < 4; ++j) acc[i][j] = (v4f){0.f, 0.f, 0.f, 0.f};

  // stage K-tile kt into buffer buf: 512 16B chunks per matrix;
  // LDS slot (row, sl) holds global chunk sl ^ ((row>>1)&3)
  auto stage = [&](int kt, int buf) {
    const int k0 = kt * BK;
    unsigned short* As = smem[buf];
    unsigned short* Bs = smem[buf] + BM * BK;
#pragma unroll
    for (int it = 0; it < 2; ++it) {
      int L = tid + it * 256;
      int row = L >> 2;
      int c = (L & 3) ^ ((row >> 1) & 3);
      int gr = m0 + row;
      gr = gr < M ? gr : (M - 1);
      gload_lds16(A + (size_t)gr * K + (k0 + c * 8), As + (size_t)L * 8);
      int gn = n0 + row;  // Nc multiple of 128 -> always valid
      gload_lds16(BT + (size_t)gn * K + (k0 + c * 8), Bs + (size_t)L * 8);
    }
  };

  const int nK = K / BK;   // 16 for K=512, 4 for K=128
  stage(0, 0);
  for (int kt = 0; kt < nK; ++kt) {
    __syncthreads();   // drains vmcnt(0): buf[kt&1] staging complete
    if (kt + 1 < nK) stage(kt + 1, (kt + 1) & 1);
    const unsigned short* As = smem[kt & 1];
    const unsigned short* Bs = smem[kt & 1] + BM * BK;
    v8bf af[4], bfr[4];
#pragma unroll
    for (int mi = 0; mi < 4; ++mi) {
      int r = wm + mi * 16 + l15;
      int s = quad ^ ((r >> 1) & 3);
      af[mi] = *(const v8bf*)(As + (r * 4 + s) * 8);
    }
#pragma unroll
    for (int ni = 0; ni < 4; ++ni) {
      int r = wn + ni * 16 + l15;
      int s = quad ^ ((r >> 1) & 3);
      bfr[ni] = *(const v8bf*)(Bs + (r * 4 + s) * 8);
    }
#pragma unroll
    for (int mi = 0; mi < 4; ++mi)
#pragma unroll
      for (int ni = 0; ni < 4; ++ni)
        acc[mi][ni] = __builtin_amdgcn_mfma_f32_16x16x32_bf16(
            af[mi], bfr[ni], acc[mi][ni], 0, 0, 0);
  }

  // Bias + activation (C/D layout: col = lane&15, row = quad*4 + reg)
  float bv[4];
#pragma unroll
  for (int ni = 0; ni < 4; ++ni) {
    int col = n0 + wn + ni * 16 + l15;
    bv[ni] = fm ? ((const float*)bias)[col]
                : bf2f(((const unsigned short*)bias)[col]);
  }
#pragma unroll
  for (int mi = 0; mi < 4; ++mi)
#pragma unroll
    for (int ni = 0; ni < 4; ++ni)
#pragma unroll
      for (int rg = 0; rg < 4; ++rg) {
        float v = acc[mi][ni][rg] + bv[ni];
        if (ACT == 0) v = v > 0.f ? v : 1.5f * v;
        if (ACT == 1) v = v > 0.f ? v : 0.f;
        acc[mi][ni][rg] = v;
      }

  if (OUTF32) {
#pragma unroll
    for (int ni = 0; ni < 4; ++ni) {
      int col = n0 + wn + ni * 16 + l15;
#pragma unroll
      for (int mi = 0; mi < 4; ++mi)
#pragma unroll
        for (int rg = 0; rg < 4; ++rg) {
          int row = m0 + wm + mi * 16 + quad * 4 + rg;
          if (row < M)
            ((float*)Cout)[(size_t)row * Nc + col] = acc[mi][ni][rg];
        }
    }
    return;
  }

  // Coalesced bf16 epilogue: two 64-row passes staged through LDS.
  unsigned short* Ct = smem[0];
  __syncthreads();
#pragma unroll
  for (int h = 0; h < 2; ++h) {
    if ((wave >> 1) == h) {
#pragma unroll
      for (int mi = 0; mi < 4; ++mi)
#pragma unroll
        for (int ni = 0; ni < 4; ++ni)
#pragma unroll
          for (int rg = 0; rg < 4; ++rg) {
            int lr = mi * 16 + quad * 4 + rg;        // 0..63
            int c = wn + ni * 16 + l15;              // 0..127
            Ct[lr * CT_SW + c] = f2bf(acc[mi][ni][rg]);
          }
    }
    __syncthreads();
    // per instruction p, 16 consecutive lanes cover one row's full 256 B
    // segment (4 complete 64 B sectors) -> no partial-sector exposure.
    int rl0 = tid >> 4;            // 0..15
    int ch = tid & 15;             // 16B chunk within the 256 B segment
#pragma unroll
    for (int p = 0; p < 4; ++p) {
      int rl = rl0 + p * 16;       // 0..63
      int grow = m0 + h * 64 + rl;
      if (grow < M) {
        v4i val = *(const v4i*)(Ct + rl * CT_SW + ch * 8);
        *(v4i*)((unsigned short*)Cout + (size_t)grow * Nc + n0 + ch * 8) = val;
      }
    }
    __syncthreads();
  }
}

// ---------------- mean pool over sorted batch (dword loads) -----------------
__global__ __launch_bounds__(256) void k_pool(
    const unsigned int* __restrict__ hu, const int* __restrict__ batch,
    const int* __restrict__ flags, unsigned int* __restrict__ pooled) {
  __shared__ int bounds[2];
  int g = blockIdx.x;
  int t = threadIdx.x;
  bool b64 = flags[2] != 0;
  if (t < 2) {
    int key = g + t;
    int lo = 0, hi = N_NODES;
    while (lo < hi) {
      int mid = (lo + hi) >> 1;
      int bv = b64 ? batch[2 * (size_t)mid] : batch[mid];
      if (bv < key) lo = mid + 1; else hi = mid;
    }
    bounds[t] = lo;
  }
  __syncthreads();
  int s0 = bounds[0], s1 = bounds[1];
  float a0 = 0.f, a1 = 0.f;
  for (int r = s0; r < s1; ++r) {
    unsigned int p = hu[(size_t)r * (D_H / 2) + t];   // dims 2t, 2t+1
    a0 += __uint_as_float((p & 0xFFFFu) << 16);
    a1 += __uint_as_float(p & 0xFFFF0000u);
  }
  float inv = 1.0f / fmaxf((float)(s1 - s0), 1.0f);
  unsigned int lo = f2bf(a0 * inv);
  unsigned int hi = f2bf(a1 * inv);
  pooled[(size_t)g * (D_H / 2) + t] = lo | (hi << 16);
}

// ---------------- row L2-normalize -----------------------------------------
__global__ __launch_bounds__(256) void k_norm(const float* __restrict__ of,
                                              const int* __restrict__ flags,
                                              void* __restrict__ out) {
  __shared__ float red[4];
  int g = blockIdx.x, t = threadIdx.x;
  float v = of[g * D_OUT + t];
  float s = v * v;
#pragma unroll
  for (int o = 32; o > 0; o >>= 1) s += __shfl_xor(s, o, 64);
  if ((t & 63) == 0) red[t >> 6] = s;
  __syncthreads();
  float tot = red[0] + red[1] + red[2] + red[3];
  float inv = 1.0f / fmaxf(sqrtf(tot), 1e-12f);
  float r = v * inv;
  if (flags[0])
    ((float*)out)[g * D_OUT + t] = r;
  else
    ((unsigned short*)out)[g * D_OUT + t] = f2bf(r);
}

// ---------------- launcher --------------------------------------------------
extern "C" void kernel_launch(void* const* d_in, const int* in_sizes, int n_in,
                              void* d_out, int out_size, void* d_ws,
                              size_t ws_size, hipStream_t stream) {
  const void* x    = d_in[0];
  const int* ei    = (const int*)d_in[1];
  const int* batch = (const int*)d_in[2];
  const void* W1 = d_in[3];
  const void* b1 = d_in[4];
  const void* W2 = d_in[5];
  const void* b2 = d_in[6];
  const void* W3 = d_in[7];
  const void* b3 = d_in[8];
  const void* W4 = d_in[9];
  const void* b4 = d_in[10];
  const void* Wl = d_in[11];
  const void* bl = d_in[12];

  char* ws = (char*)d_ws;
  size_t off = 0;
  auto alloc = [&](size_t bytes) {
    void* p = ws + off;
    off += (bytes + 255) & ~(size_t)255;
    return p;
  };
  int* flags           = (int*)alloc(64);
  unsigned short* W1T  = (unsigned short*)alloc((size_t)D_IN * D_H * 2);
  unsigned short* W2T  = (unsigned short*)alloc((size_t)D_H * D_H * 2);
  unsigned short* W3T  = (unsigned short*)alloc((size_t)D_H * D_H * 2);
  unsigned short* W4T  = (unsigned short*)alloc((size_t)D_H * D_H * 2);
  unsigned short* WlT  = (unsigned short*)alloc((size_t)D_H * D_OUT * 2);
  unsigned int* pooled = (unsigned int*)alloc((size_t)N_GRAPHS * D_H * 2);
  float* outf          = (float*)alloc((size_t)N_GRAPHS * D_OUT * 4);
  int* deg    = (int*)alloc((size_t)N_NODES * 4);
  int* rowptr = (int*)alloc(((size_t)N_NODES + 1) * 4);
  int* cur    = (int*)alloc((size_t)N_NODES * 4);
  int* part   = (int*)alloc((size_t)NBLK * 4);
  int* elist  = (int*)alloc((size_t)N_EDGES * 4);
  // two big slots (51.2 MB each), aliased:
  //   S1: xi (int16 x, 12.8MB) -> dead after gather -> hA(bf16)
  //   S2: h0(12.8MB)           -> dead after GEMM1  -> hB(bf16)
  void* S1 = alloc((size_t)N_NODES * D_H * 2);
  void* S2 = alloc((size_t)N_NODES * D_H * 2);
  unsigned int* xi   = (unsigned int*)S1;
  unsigned short* hA = (unsigned short*)S1;
  unsigned int* h0u  = (unsigned int*)S2;
  unsigned short* h0 = (unsigned short*)S2;
  unsigned short* hB = (unsigned short*)S2;

  k_prep<<<NBLK, 256, 0, stream>>>(x, ei, batch, deg, flags);

  k_transpose_all<<<(983040 + 255) / 256, 256, 0, stream>>>(
      W1, W2, W3, W4, Wl, W1T, W2T, W3T, W4T, WlT, flags);
  k_cvtx<<<(N_NODES * D_IN / 2 + 255) / 256, 256, 0, stream>>>(x, flags, xi);

  // CSR build + gather aggregation
  k_count<<<(N_EDGES + 255) / 256, 256, 0, stream>>>(ei, deg, flags, N_EDGES);
  k_scanA<<<NBLK, 256, 0, stream>>>(deg, rowptr, part);
  k_scanB<<<1, 256, 0, stream>>>(part, rowptr);
  k_scanC<<<NBLK, 256, 0, stream>>>(rowptr, part, cur);
  k_fill<<<(N_EDGES + 255) / 256, 256, 0, stream>>>(ei, cur, elist, flags, N_EDGES);
  k_gather<<<(N_NODES + 3) / 4, 256, 0, stream>>>(xi, rowptr, elist, h0u);

  const int gBig = 8 * MT_PER_XCD * 4;   // 1568 XCD-swizzled blocks
  gemm_bt<0, false, true><<<gBig, 256, 0, stream>>>(h0, W1T, b1, flags, hA, N_NODES, D_IN, D_H);
  gemm_bt<1, false, true><<<gBig, 256, 0, stream>>>(hA, W2T, b2, flags, hB, N_NODES, D_H, D_H);
  gemm_bt<1, false, true><<<gBig, 256, 0, stream>>>(hB, W3T, b3, flags, hA, N_NODES, D_H, D_H);
  gemm_bt<2, false, true><<<gBig, 256, 0, stream>>>(hA, W4T, b4, flags, hB, N_NODES, D_H, D_H);

  k_pool<<<N_GRAPHS, 256, 0, stream>>>((const unsigned int*)hB, batch, flags, pooled);

  dim3 g5(D_OUT / BN, N_GRAPHS / BM);
  gemm_bt<2, true, false><<<g5, 256, 0, stream>>>((const unsigned short*)pooled, WlT, bl, flags, outf, N_GRAPHS, D_H, D_OUT);

  k_norm<<<N_GRAPHS, 256, 0, stream>>>(outf, flags, (unsigned short*)d_out);
}

// Round 14
// 460.511 us; speedup vs baseline: 1.0785x; 1.0785x over previous
//
#include <hip/hip_runtime.h>
#include <hip/hip_bf16.h>
#include <cstdint>
#include <cstddef>

#define N_NODES 50000
#define N_EDGES 800000
#define D_IN 128
#define D_H 512
#define D_OUT 256
#define N_GRAPHS 512

#define BM 128
#define BN 128
#define BK 32
#define NBLK ((N_NODES + 255) / 256)   // 196
#define CT_SW 132                      // C-tile LDS stride in ushorts (264 B)
#define N_MT 391                       // m-tiles for M=50000
#define MT_PER_XCD 49                  // ceil(391/8)

// fixed-point scales: x quantized to int16 (scale 2^12, |x|<8 guaranteed by
// clamp), accumulated in int32 -> bitwise-deterministic aggregation.
#define XQ_SCALE 4096.0f
#define XQ_INV (1.0f / 4096.0f)

typedef __bf16 v8bf __attribute__((ext_vector_type(8)));
typedef float v4f __attribute__((ext_vector_type(4)));
typedef int v4i __attribute__((ext_vector_type(4)));

__device__ __forceinline__ float bf2f(unsigned short b) {
  return __uint_as_float(((unsigned int)b) << 16);
}
__device__ __forceinline__ unsigned short f2bf(float f) {
  unsigned int u = __float_as_uint(f);
  u += 0x7FFFu + ((u >> 16) & 1u);   // RNE
  return (unsigned short)(u >> 16);
}

__device__ __forceinline__ void gload_lds16(const void* g, void* l) {
  __builtin_amdgcn_global_load_lds(
      (const __attribute__((address_space(1))) void*)g,
      (__attribute__((address_space(3))) void*)l, 16, 0, 0);
}

// ---------------- prep: zero deg + dtype detect (block 0) -------------------
__global__ __launch_bounds__(256) void k_prep(const void* __restrict__ x,
                                              const void* __restrict__ ei,
                                              const void* __restrict__ batch,
                                              int* __restrict__ deg,
                                              int* __restrict__ flags) {
  int i = blockIdx.x * 256 + threadIdx.x;
  if (i < N_NODES) deg[i] = 0;
  if (blockIdx.x != 0) return;
  __shared__ int cnt[3];
  int t = threadIdx.x;
  if (t < 3) cnt[t] = 0;
  __syncthreads();
  const unsigned short* xs = (const unsigned short*)x;
  int c0 = 0;
  for (int k = t; k < 4096; k += 256) {
    unsigned int e = (xs[k] >> 7) & 0xFFu;
    if (e >= 0x90u) c0++;   // |v|>=2^17 as bf16: impossible for N(0,1)
  }
  atomicAdd(&cnt[0], c0);
  const int* e32 = (const int*)ei;
  int c1 = 0;
  for (int k = t; k < 512; k += 256)
    if (e32[2 * k + 1] != 0) c1++;   // int64 -> high words all zero
  atomicAdd(&cnt[1], c1);
  const int* b32 = (const int*)batch;
  int c2 = 0;
  {
    int w = (N_NODES - 512) + 2 * t + 1;   // odd word near tail, < N_NODES
    if (b32[w] != 0) c2++;
  }
  atomicAdd(&cnt[2], c2);
  __syncthreads();
  if (t == 0) {
    flags[0] = (cnt[0] > 16) ? 1 : 0;
    flags[1] = (cnt[1] == 0) ? 1 : 0;
    flags[2] = (cnt[2] == 0) ? 1 : 0;
  }
}

// ---------------- fused weight transposes (B^T layout) ----------------------
__global__ void k_transpose_all(const void* W1, const void* W2, const void* W3,
                                const void* W4, const void* Wl,
                                unsigned short* W1T, unsigned short* W2T,
                                unsigned short* W3T, unsigned short* W4T,
                                unsigned short* WlT,
                                const int* __restrict__ flags) {
  int i = blockIdx.x * 256 + threadIdx.x;
  const void* src;
  unsigned short* dst;
  int R, C, j;
  if (i < 65536)            { src = W1; dst = W1T; R = 128; C = 512; j = i; }
  else if (i < 327680)      { src = W2; dst = W2T; R = 512; C = 512; j = i - 65536; }
  else if (i < 589824)      { src = W3; dst = W3T; R = 512; C = 512; j = i - 327680; }
  else if (i < 851968)      { src = W4; dst = W4T; R = 512; C = 512; j = i - 589824; }
  else if (i < 983040)      { src = Wl; dst = WlT; R = 512; C = 256; j = i - 851968; }
  else return;
  int r = j / C, c = j - r * C;
  unsigned short v = flags[0] ? f2bf(((const float*)src)[j])
                              : ((const unsigned short*)src)[j];
  dst[c * R + r] = v;
}

// ---------------- x -> packed int16 fixed-point (scale 2^12) ----------------
__global__ __launch_bounds__(256) void k_cvtx(const void* __restrict__ x,
                                              const int* __restrict__ flags,
                                              unsigned int* __restrict__ xi) {
  int i = blockIdx.x * 256 + threadIdx.x;   // dword index (2 values)
  if (i >= N_NODES * D_IN / 2) return;
  float v0, v1;
  if (flags[0]) {
    const float* xf = (const float*)x + (size_t)i * 2;
    v0 = xf[0];
    v1 = xf[1];
  } else {
    unsigned int p = ((const unsigned int*)x)[i];
    v0 = __uint_as_float((p & 0xFFFFu) << 16);
    v1 = __uint_as_float(p & 0xFFFF0000u);
  }
  int q0 = __float2int_rn(fminf(fmaxf(v0, -7.99f), 7.99f) * XQ_SCALE);
  int q1 = __float2int_rn(fminf(fmaxf(v1, -7.99f), 7.99f) * XQ_SCALE);
  xi[i] = ((unsigned int)q0 & 0xFFFFu) | ((unsigned int)q1 << 16);
}

// ---------------- CSR build -------------------------------------------------
__global__ void k_count(const int* __restrict__ ei, int* __restrict__ deg,
                        const int* __restrict__ flags, int ne) {
  int e = blockIdx.x * 256 + threadIdx.x;
  if (e >= ne) return;
  int d = flags[1] ? ei[2 * ((size_t)ne + e)] : ei[(size_t)ne + e];
  atomicAdd(&deg[d], 1);
}

__global__ __launch_bounds__(256) void k_scanA(const int* __restrict__ deg,
                                               int* __restrict__ rowptr,
                                               int* __restrict__ part) {
  __shared__ int sh[256];
  int t = threadIdx.x;
  int i = blockIdx.x * 256 + t;
  int v = (i < N_NODES) ? deg[i] : 0;
  sh[t] = v;
  __syncthreads();
  for (int o = 1; o < 256; o <<= 1) {
    int a = sh[t];
    int b = (t >= o) ? sh[t - o] : 0;
    __syncthreads();
    sh[t] = a + b;
    __syncthreads();
  }
  if (i < N_NODES) rowptr[i] = sh[t] - v;   // local exclusive
  if (t == 255) part[blockIdx.x] = sh[255];
}

__global__ __launch_bounds__(256) void k_scanB(int* __restrict__ part,
                                               int* __restrict__ rowptr) {
  __shared__ int sh[256];
  int t = threadIdx.x;
  int v = (t < NBLK) ? part[t] : 0;
  sh[t] = v;
  __syncthreads();
  for (int o = 1; o < 256; o <<= 1) {
    int a = sh[t];
    int b = (t >= o) ? sh[t - o] : 0;
    __syncthreads();
    sh[t] = a + b;
    __syncthreads();
  }
  if (t < NBLK) part[t] = sh[t] - v;   // exclusive base per block
  if (t == 0) rowptr[N_NODES] = sh[255];
}

__global__ __launch_bounds__(256) void k_scanC(int* __restrict__ rowptr,
                                               const int* __restrict__ part,
                                               int* __restrict__ cur) {
  int i = blockIdx.x * 256 + threadIdx.x;
  if (i < N_NODES) {
    int r = rowptr[i] + part[blockIdx.x];
    rowptr[i] = r;
    cur[i] = r;
  }
}

// Full-parallel fill, plain loads+stores (measured best: R7; nt variants and
// XCD-pinning all regressed in R8-R10).
__global__ void k_fill(const int* __restrict__ ei, int* __restrict__ cur,
                       int* __restrict__ elist, const int* __restrict__ flags,
                       int ne) {
  int e = blockIdx.x * 256 + threadIdx.x;
  if (e >= ne) return;
  bool fe64 = flags[1] != 0;
  int s = fe64 ? ei[2 * (size_t)e] : ei[e];
  int d = fe64 ? ei[2 * ((size_t)ne + e)] : ei[(size_t)ne + e];
  int pos = atomicAdd(&cur[d], 1);
  elist[pos] = s;
}

// ---------------- gather aggregation (one wave per node, int16 source) ------
// readlane -> SGPR row base (no ds_bpermute); int16 adds, int32 accumulate.
__global__ __launch_bounds__(256) void k_gather(
    const unsigned int* __restrict__ xi, const int* __restrict__ rowptr,
    const int* __restrict__ elist, unsigned int* __restrict__ h0) {
  int node = blockIdx.x * 4 + (threadIdx.x >> 6);
  if (node >= N_NODES) return;
  int lane = threadIdx.x & 63;
  int s0 = rowptr[node], s1 = rowptr[node + 1];
  unsigned int px = xi[(size_t)node * (D_IN / 2) + lane];
  int a0 = (int)(short)(px & 0xFFFFu);
  int a1 = (int)px >> 16;
  for (int j0 = s0; j0 < s1; j0 += 64) {
    int jj = j0 + lane;
    int ev = (jj < s1) ? elist[jj] : 0;
    int cnt = s1 - j0;
    cnt = cnt < 64 ? cnt : 64;
    for (int j = 0; j < cnt; ++j) {
      int s = __builtin_amdgcn_readlane(ev, j);    // wave-uniform SGPR
      unsigned int p = xi[(size_t)s * (D_IN / 2) + lane];
      a0 += (int)(short)(p & 0xFFFFu);
      a1 += (int)p >> 16;
    }
  }
  unsigned int lo = f2bf((float)a0 * XQ_INV);
  unsigned int hi = f2bf((float)a1 * XQ_INV);
  h0[(size_t)node * (D_IN / 2) + lane] = lo | (hi << 16);
}

// ---------------- MFMA GEMM: C = act(A @ W + bias), BK=32 dbuf -------------
// Swizzle g(r)=(r>>1)&3 (conflict-free, R11). Epilogue sector-complete store
// map (R12: WRITE 97->52 MB). __launch_bounds__(256,4): VGPR 64 — (256,5)
// regressed (R13: VGPR squeezed to 48, acc shuffling, no occupancy gain).
// ACT: 0 = LeakyReLU(1.5), 1 = ReLU, 2 = none. OUTF32: write f32 else bf16.
template <int ACT, bool OUTF32, bool SWZ>
__global__ __launch_bounds__(256, 4) void gemm_bt(
    const unsigned short* __restrict__ A,
    const unsigned short* __restrict__ BT,
    const void* __restrict__ bias, const int* __restrict__ flags,
    void* __restrict__ Cout, int M, int K, int Nc) {
  __shared__ __align__(16) unsigned short smem[2][BM * BK + BN * BK];  // 32 KB

  const int tid  = threadIdx.x;
  const int wave = tid >> 6;
  const int lane = tid & 63;
  const int quad = lane >> 4;
  const int l15  = lane & 15;
  int m0, n0;
  if (SWZ) {
    int xcd = blockIdx.x & 7;
    int l = blockIdx.x >> 3;                 // 0..195
    int mt = xcd * MT_PER_XCD + (l >> 2);    // 49 m-tiles per XCD
    if (mt >= N_MT) return;                  // 8 padded blocks exit
    m0 = mt * BM;
    n0 = (l & 3) * BN;
  } else {
    n0 = blockIdx.x * BN;
    m0 = blockIdx.y * BM;
  }
  const int wm = (wave >> 1) * 64;
  const int wn = (wave & 1) * 64;
  const bool fm = flags[0] != 0;

  v4f acc[4][4];
#pragma unroll
  for (int i = 0; i < 4; ++i)
#pragma unroll
    for (int j = 0; j < 4; ++j) acc[i][j] = (v4f){0.f, 0.f, 0.f, 0.f};

  // stage K-tile kt into buffer buf: 512 16B chunks per matrix;
  // LDS slot (row, sl) holds global chunk sl ^ ((row>>1)&3)
  auto stage = [&](int kt, int buf) {
    const int k0 = kt * BK;
    unsigned short* As = smem[buf];
    unsigned short* Bs = smem[buf] + BM * BK;
#pragma unroll
    for (int it = 0; it < 2; ++it) {
      int L = tid + it * 256;
      int row = L >> 2;
      int c = (L & 3) ^ ((row >> 1) & 3);
      int gr = m0 + row;
      gr = gr < M ? gr : (M - 1);
      gload_lds16(A + (size_t)gr * K + (k0 + c * 8), As + (size_t)L * 8);
      int gn = n0 + row;  // Nc multiple of 128 -> always valid
      gload_lds16(BT + (size_t)gn * K + (k0 + c * 8), Bs + (size_t)L * 8);
    }
  };

  const int nK = K / BK;   // 16 for K=512, 4 for K=128
  stage(0, 0);
  for (int kt = 0; kt < nK; ++kt) {
    __syncthreads();   // drains vmcnt(0): buf[kt&1] staging complete
    if (kt + 1 < nK) stage(kt + 1, (kt + 1) & 1);
    const unsigned short* As = smem[kt & 1];
    const unsigned short* Bs = smem[kt & 1] + BM * BK;
    v8bf af[4], bfr[4];
#pragma unroll
    for (int mi = 0; mi < 4; ++mi) {
      int r = wm + mi * 16 + l15;
      int s = quad ^ ((r >> 1) & 3);
      af[mi] = *(const v8bf*)(As + (r * 4 + s) * 8);
    }
#pragma unroll
    for (int ni = 0; ni < 4; ++ni) {
      int r = wn + ni * 16 + l15;
      int s = quad ^ ((r >> 1) & 3);
      bfr[ni] = *(const v8bf*)(Bs + (r * 4 + s) * 8);
    }
#pragma unroll
    for (int mi = 0; mi < 4; ++mi)
#pragma unroll
      for (int ni = 0; ni < 4; ++ni)
        acc[mi][ni] = __builtin_amdgcn_mfma_f32_16x16x32_bf16(
            af[mi], bfr[ni], acc[mi][ni], 0, 0, 0);
  }

  // Bias + activation (C/D layout: col = lane&15, row = quad*4 + reg)
  float bv[4];
#pragma unroll
  for (int ni = 0; ni < 4; ++ni) {
    int col = n0 + wn + ni * 16 + l15;
    bv[ni] = fm ? ((const float*)bias)[col]
                : bf2f(((const unsigned short*)bias)[col]);
  }
#pragma unroll
  for (int mi = 0; mi < 4; ++mi)
#pragma unroll
    for (int ni = 0; ni < 4; ++ni)
#pragma unroll
      for (int rg = 0; rg < 4; ++rg) {
        float v = acc[mi][ni][rg] + bv[ni];
        if (ACT == 0) v = v > 0.f ? v : 1.5f * v;
        if (ACT == 1) v = v > 0.f ? v : 0.f;
        acc[mi][ni][rg] = v;
      }

  if (OUTF32) {
#pragma unroll
    for (int ni = 0; ni < 4; ++ni) {
      int col = n0 + wn + ni * 16 + l15;
#pragma unroll
      for (int mi = 0; mi < 4; ++mi)
#pragma unroll
        for (int rg = 0; rg < 4; ++rg) {
          int row = m0 + wm + mi * 16 + quad * 4 + rg;
          if (row < M)
            ((float*)Cout)[(size_t)row * Nc + col] = acc[mi][ni][rg];
        }
    }
    return;
  }

  // Coalesced bf16 epilogue: two 64-row passes staged through LDS.
  unsigned short* Ct = smem[0];
  __syncthreads();
#pragma unroll
  for (int h = 0; h < 2; ++h) {
    if ((wave >> 1) == h) {
#pragma unroll
      for (int mi = 0; mi < 4; ++mi)
#pragma unroll
        for (int ni = 0; ni < 4; ++ni)
#pragma unroll
          for (int rg = 0; rg < 4; ++rg) {
            int lr = mi * 16 + quad * 4 + rg;        // 0..63
            int c = wn + ni * 16 + l15;              // 0..127
            Ct[lr * CT_SW + c] = f2bf(acc[mi][ni][rg]);
          }
    }
    __syncthreads();
    // per instruction p, 16 consecutive lanes cover one row's full 256 B
    // segment (4 complete 64 B sectors) -> no partial-sector exposure.
    int rl0 = tid >> 4;            // 0..15
    int ch = tid & 15;             // 16B chunk within the 256 B segment
#pragma unroll
    for (int p = 0; p < 4; ++p) {
      int rl = rl0 + p * 16;       // 0..63
      int grow = m0 + h * 64 + rl;
      if (grow < M) {
        v4i val = *(const v4i*)(Ct + rl * CT_SW + ch * 8);
        *(v4i*)((unsigned short*)Cout + (size_t)grow * Nc + n0 + ch * 8) = val;
      }
    }
    __syncthreads();
  }
}

// ---------------- mean pool over sorted batch (dword loads) -----------------
__global__ __launch_bounds__(256) void k_pool(
    const unsigned int* __restrict__ hu, const int* __restrict__ batch,
    const int* __restrict__ flags, unsigned int* __restrict__ pooled) {
  __shared__ int bounds[2];
  int g = blockIdx.x;
  int t = threadIdx.x;
  bool b64 = flags[2] != 0;
  if (t < 2) {
    int key = g + t;
    int lo = 0, hi = N_NODES;
    while (lo < hi) {
      int mid = (lo + hi) >> 1;
      int bv = b64 ? batch[2 * (size_t)mid] : batch[mid];
      if (bv < key) lo = mid + 1; else hi = mid;
    }
    bounds[t] = lo;
  }
  __syncthreads();
  int s0 = bounds[0], s1 = bounds[1];
  float a0 = 0.f, a1 = 0.f;
  for (int r = s0; r < s1; ++r) {
    unsigned int p = hu[(size_t)r * (D_H / 2) + t];   // dims 2t, 2t+1
    a0 += __uint_as_float((p & 0xFFFFu) << 16);
    a1 += __uint_as_float(p & 0xFFFF0000u);
  }
  float inv = 1.0f / fmaxf((float)(s1 - s0), 1.0f);
  unsigned int lo = f2bf(a0 * inv);
  unsigned int hi = f2bf(a1 * inv);
  pooled[(size_t)g * (D_H / 2) + t] = lo | (hi << 16);
}

// ---------------- row L2-normalize -----------------------------------------
__global__ __launch_bounds__(256) void k_norm(const float* __restrict__ of,
                                              const int* __restrict__ flags,
                                              void* __restrict__ out) {
  __shared__ float red[4];
  int g = blockIdx.x, t = threadIdx.x;
  float v = of[g * D_OUT + t];
  float s = v * v;
#pragma unroll
  for (int o = 32; o > 0; o >>= 1) s += __shfl_xor(s, o, 64);
  if ((t & 63) == 0) red[t >> 6] = s;
  __syncthreads();
  float tot = red[0] + red[1] + red[2] + red[3];
  float inv = 1.0f / fmaxf(sqrtf(tot), 1e-12f);
  float r = v * inv;
  if (flags[0])
    ((float*)out)[g * D_OUT + t] = r;
  else
    ((unsigned short*)out)[g * D_OUT + t] = f2bf(r);
}

// ---------------- launcher --------------------------------------------------
extern "C" void kernel_launch(void* const* d_in, const int* in_sizes, int n_in,
                              void* d_out, int out_size, void* d_ws,
                              size_t ws_size, hipStream_t stream) {
  const void* x    = d_in[0];
  const int* ei    = (const int*)d_in[1];
  const int* batch = (const int*)d_in[2];
  const void* W1 = d_in[3];
  const void* b1 = d_in[4];
  const void* W2 = d_in[5];
  const void* b2 = d_in[6];
  const void* W3 = d_in[7];
  const void* b3 = d_in[8];
  const void* W4 = d_in[9];
  const void* b4 = d_in[10];
  const void* Wl = d_in[11];
  const void* bl = d_in[12];

  char* ws = (char*)d_ws;
  size_t off = 0;
  auto alloc = [&](size_t bytes) {
    void* p = ws + off;
    off += (bytes + 255) & ~(size_t)255;
    return p;
  };
  int* flags           = (int*)alloc(64);
  unsigned short* W1T  = (unsigned short*)alloc((size_t)D_IN * D_H * 2);
  unsigned short* W2T  = (unsigned short*)alloc((size_t)D_H * D_H * 2);
  unsigned short* W3T  = (unsigned short*)alloc((size_t)D_H * D_H * 2);
  unsigned short* W4T  = (unsigned short*)alloc((size_t)D_H * D_H * 2);
  unsigned short* WlT  = (unsigned short*)alloc((size_t)D_H * D_OUT * 2);
  unsigned int* pooled = (unsigned int*)alloc((size_t)N_GRAPHS * D_H * 2);
  float* outf          = (float*)alloc((size_t)N_GRAPHS * D_OUT * 4);
  int* deg    = (int*)alloc((size_t)N_NODES * 4);
  int* rowptr = (int*)alloc(((size_t)N_NODES + 1) * 4);
  int* cur    = (int*)alloc((size_t)N_NODES * 4);
  int* part   = (int*)alloc((size_t)NBLK * 4);
  int* elist  = (int*)alloc((size_t)N_EDGES * 4);
  // two big slots (51.2 MB each), aliased:
  //   S1: xi (int16 x, 12.8MB) -> dead after gather -> hA(bf16)
  //   S2: h0(12.8MB)           -> dead after GEMM1  -> hB(bf16)
  void* S1 = alloc((size_t)N_NODES * D_H * 2);
  void* S2 = alloc((size_t)N_NODES * D_H * 2);
  unsigned int* xi   = (unsigned int*)S1;
  unsigned short* hA = (unsigned short*)S1;
  unsigned int* h0u  = (unsigned int*)S2;
  unsigned short* h0 = (unsigned short*)S2;
  unsigned short* hB = (unsigned short*)S2;

  k_prep<<<NBLK, 256, 0, stream>>>(x, ei, batch, deg, flags);

  k_transpose_all<<<(983040 + 255) / 256, 256, 0, stream>>>(
      W1, W2, W3, W4, Wl, W1T, W2T, W3T, W4T, WlT, flags);
  k_cvtx<<<(N_NODES * D_IN / 2 + 255) / 256, 256, 0, stream>>>(x, flags, xi);

  // CSR build + gather aggregation
  k_count<<<(N_EDGES + 255) / 256, 256, 0, stream>>>(ei, deg, flags, N_EDGES);
  k_scanA<<<NBLK, 256, 0, stream>>>(deg, rowptr, part);
  k_scanB<<<1, 256, 0, stream>>>(part, rowptr);
  k_scanC<<<NBLK, 256, 0, stream>>>(rowptr, part, cur);
  k_fill<<<(N_EDGES + 255) / 256, 256, 0, stream>>>(ei, cur, elist, flags, N_EDGES);
  k_gather<<<(N_NODES + 3) / 4, 256, 0, stream>>>(xi, rowptr, elist, h0u);

  const int gBig = 8 * MT_PER_XCD * 4;   // 1568 XCD-swizzled blocks
  gemm_bt<0, false, true><<<gBig, 256, 0, stream>>>(h0, W1T, b1, flags, hA, N_NODES, D_IN, D_H);
  gemm_bt<1, false, true><<<gBig, 256, 0, stream>>>(hA, W2T, b2, flags, hB, N_NODES, D_H, D_H);
  gemm_bt<1, false, true><<<gBig, 256, 0, stream>>>(hB, W3T, b3, flags, hA, N_NODES, D_H, D_H);
  gemm_bt<2, false, true><<<gBig, 256, 0, stream>>>(hA, W4T, b4, flags, hB, N_NODES, D_H, D_H);

  k_pool<<<N_GRAPHS, 256, 0, stream>>>((const unsigned int*)hB, batch, flags, pooled);

  dim3 g5(D_OUT / BN, N_GRAPHS / BM);
  gemm_bt<2, true, false><<<g5, 256, 0, stream>>>((const unsigned short*)pooled, WlT, bl, flags, outf, N_GRAPHS, D_H, D_OUT);

  k_norm<<<N_GRAPHS, 256, 0, stream>>>(outf, flags, (unsigned short*)d_out);
}